// Round 15
// baseline (133.572 us; speedup 1.0000x reference)
//
#include <hip/hip_runtime.h>
#include <hip/hip_bf16.h>
#include <stdint.h>

typedef __bf16 bf16_t;
typedef __bf16 bf16x4 __attribute__((ext_vector_type(4)));
typedef __bf16 bf16x8 __attribute__((ext_vector_type(8)));
typedef float  f32x4  __attribute__((ext_vector_type(4)));

#define DIM    1024
#define NTOK   4096
#define NB     8
#define ROWS   (NB*NTOK)   // 32768
#define QKVC   384
#define INNER  128

// global -> LDS direct copy, 16B per lane (dest = wave-uniform base + lane*16)
#define GLD16(g, l) __builtin_amdgcn_global_load_lds( \
    (const __attribute__((address_space(1))) void*)(g), \
    (__attribute__((address_space(3))) void*)(l), 16, 0, 0)

// workspace offsets (bytes)
#define OFF_WQ    131072u      // 384*1024 bf16   (768 KB)
#define OFF_XB    1048576u     // 32768*1024 bf16 (64 MB)
#define OFF_QKV   68157440u    // 32768*384 bf16  (24 MB)
#define OFF_STATS 93323264u    // 512 chunks * 2304 f32
#define OFF_ATTN  98041856u    // 8*8*16*16 f32
#define OFF_WEFF  98107392u    // 8*1024*128 bf16

// ---------- kernel 0: merged  [blocks 0..8191] RMSNorm-fold x->bf16
//                      [blocks 8192..8575] w_qkv*norm_weight->bf16 ----------
// Measured ~31 us in R7 (at its 194MB HBM floor).
__global__ __launch_bounds__(256) void k_prep(const float* __restrict__ x,
    const float* __restrict__ wq, const float* __restrict__ nw,
    bf16_t* __restrict__ xb, bf16_t* __restrict__ wqb)
{
    if (blockIdx.x >= 8192) {               // wconv part
        int o = blockIdx.x - 8192;          // 384 rows
        int c = threadIdx.x * 4;
        float4 wv = *reinterpret_cast<const float4*>(wq + (size_t)o*DIM + c);
        float4 nv = *reinterpret_cast<const float4*>(nw + c);
        bf16_t* dst = wqb + (size_t)o*DIM + c;
        dst[0]=(bf16_t)(wv.x*nv.x); dst[1]=(bf16_t)(wv.y*nv.y);
        dst[2]=(bf16_t)(wv.z*nv.z); dst[3]=(bf16_t)(wv.w*nv.w);
        return;
    }
    int row  = blockIdx.x*4 + (threadIdx.x >> 6);
    int lane = threadIdx.x & 63;
    const float4* xv = reinterpret_cast<const float4*>(x + (size_t)row*DIM);
    float4 u[4];
    float ss = 0.f;
    #pragma unroll
    for (int i = 0; i < 4; i++) {
        u[i] = xv[lane + 64*i];
        ss += u[i].x*u[i].x + u[i].y*u[i].y + u[i].z*u[i].z + u[i].w*u[i].w;
    }
    #pragma unroll
    for (int d = 1; d < 64; d <<= 1) ss += __shfl_xor(ss, d, 64);
    float s = rsqrtf(ss*(1.0f/DIM) + 1e-6f);
    bf16_t* dst = xb + (size_t)row*DIM;
    #pragma unroll
    for (int i = 0; i < 4; i++) {
        bf16x4 v;
        v[0]=(bf16_t)(u[i].x*s); v[1]=(bf16_t)(u[i].y*s);
        v[2]=(bf16_t)(u[i].z*s); v[3]=(bf16_t)(u[i].w*s);
        *reinterpret_cast<bf16x4*>(dst + (lane + 64*i)*4) = v;
    }
}

// ---------- kernel 1: QKV GEMM — m97-exact, bf16 both operands ----------
// Differential test after R8..R14 (7 fused-fp32-A schedules all pinned at
// ~330 TF/CU, MfmaUtil 11-13%): same verified structure, verified dtype.
// 128^2 tile, BK=64, 256 thr, single 32KB LDS, 2-syncthreads loop, GLD16
// both sides (4+4/thread; linear dest, inverse-swizzled source slot
// (t&7)^((t>>3)&7), read slot (kk*4+lg)^(lr&7) — 0-conflict per R14).
// Grid 768 XCD-bijective: each trio shares its x-panel via one XCD's L2.
__global__ __launch_bounds__(256) void k_qkv_gemm(const bf16_t* __restrict__ xb,
    const bf16_t* __restrict__ wqb, bf16_t* __restrict__ qkv)
{
    __shared__ bf16_t Al[128*64];      // 16 KB
    __shared__ bf16_t Bl[128*64];      // 16 KB
    int b0 = blockIdx.x;               // 768 = 256mt x 3nt
    int orig = (b0 & 7)*96 + (b0 >> 3);   // bijective XCD swizzle (768%8==0)
    int mt = orig / 3, nt = orig % 3;
    int row0 = mt*128, col0 = nt*128;
    int t = threadIdx.x;
    int lane = t & 63, lr = lane & 15, lg = lane >> 4;
    int w = t >> 6, wm = w >> 1, wn = w & 1;   // 2x2 wave grid, 64x64/wave

    // staging: instr j covers rows j*32+(t>>3); dest j*2048 + t*8 (linear);
    // source k-slot (t&7)^((t>>3)&7)   [row&7 == (t>>3)&7]
    int s8 = (t & 7) ^ ((t >> 3) & 7);
    const bf16_t* asrc = xb  + (size_t)(row0 + (t >> 3))*DIM + s8*8;
    const bf16_t* bsrc = wqb + (size_t)(col0 + (t >> 3))*DIM + s8*8;

    f32x4 acc[4][4] = {};

    for (int kt = 0; kt < 16; kt++) {
        __syncthreads();               // prev compute done before overwrite
        #pragma unroll
        for (int j = 0; j < 4; j++) {
            GLD16(asrc + (size_t)(j*32)*DIM + kt*64, &Al[j*2048 + t*8]);
            GLD16(bsrc + (size_t)(j*32)*DIM + kt*64, &Bl[j*2048 + t*8]);
        }
        __syncthreads();               // staging drained (vmcnt0 in syncthreads)
        #pragma unroll
        for (int kk = 0; kk < 2; kk++) {
            bf16x8 af[4], bfr[4];
            #pragma unroll
            for (int mi = 0; mi < 4; mi++) {
                int rowA = wm*64 + mi*16 + lr;          // rowA&7 == lr&7
                int p = (kk*4 + lg) ^ (lr & 7);
                af[mi] = *reinterpret_cast<const bf16x8*>(&Al[rowA*64 + p*8]);
            }
            #pragma unroll
            for (int ni = 0; ni < 4; ni++) {
                int rowB = wn*64 + ni*16 + lr;          // rowB&7 == lr&7
                int p = (kk*4 + lg) ^ (lr & 7);
                bfr[ni] = *reinterpret_cast<const bf16x8*>(&Bl[rowB*64 + p*8]);
            }
            #pragma unroll
            for (int mi = 0; mi < 4; mi++)
                #pragma unroll
                for (int ni = 0; ni < 4; ni++)
                    acc[mi][ni] = __builtin_amdgcn_mfma_f32_16x16x32_bf16(
                        af[mi], bfr[ni], acc[mi][ni], 0, 0, 0);
        }
    }

    #pragma unroll
    for (int mi = 0; mi < 4; mi++)
        #pragma unroll
        for (int ni = 0; ni < 4; ni++) {
            int col_g = col0 + wn*64 + ni*16 + lr;
            #pragma unroll
            for (int rr = 0; rr < 4; rr++) {
                int row_g = row0 + wm*64 + mi*16 + lg*4 + rr;
                qkv[(size_t)row_g*QKVC + col_g] = (bf16_t)acc[mi][ni][rr];
            }
        }
}

// ---------- kernel 2: per-(b,chunk) Gram + sumsq partials ----------
__global__ __launch_bounds__(256) void k_stats(const bf16_t* __restrict__ qkv,
    float* __restrict__ stats)
{
    __shared__ bf16_t qk[64*264];   // 64 tokens x 256 (q,k cols) + pad 8
    int bid = blockIdx.x;           // 512 = 8b * 64ch
    int b = bid >> 6, ch = bid & 63;
    int t = threadIdx.x;
    #pragma unroll
    for (int rd = 0; rd < 8; rd++) {
        int tok = (t >> 5) + 8*rd;
        int c8  = (t & 31) * 8;     // cols 0..255 = q,k
        *reinterpret_cast<uint4*>(&qk[tok*264 + c8]) =
            *reinterpret_cast<const uint4*>(
                qkv + ((size_t)b*NTOK + ch*64 + tok)*QKVC + c8);
    }
    __syncthreads();
    int h = t >> 5, s = t & 31, i0 = (s >> 4)*8, j = s & 15;
    float gram[8] = {}, qsq[8] = {}, ksq = 0.f;
    for (int tok = 0; tok < 64; tok++) {
        bf16x8 q8 = *reinterpret_cast<const bf16x8*>(&qk[tok*264 + h*16 + i0]);
        float kf = (float)qk[tok*264 + 128 + h*16 + j];
        ksq += kf*kf;
        #pragma unroll
        for (int m = 0; m < 8; m++) {
            float qf = (float)q8[m];
            gram[m] += qf*kf;
            qsq[m]  += qf*qf;
        }
    }
    float* base = stats + ((size_t)(b*64 + ch)*8 + h)*288;
    #pragma unroll
    for (int m = 0; m < 8; m++) base[(i0 + m)*16 + j] = gram[m];
    if (j == 0) {
        #pragma unroll
        for (int m = 0; m < 8; m++) base[256 + i0 + m] = qsq[m];
    }
    if (s < 16) base[272 + j] = ksq;
}

// ---------- kernel 3: reduce partials, l2-normalize, temperature, softmax ----------
__global__ __launch_bounds__(256) void k_attn(const float* __restrict__ stats,
    const float* __restrict__ temp, float* __restrict__ attn)
{
    int bid = blockIdx.x;           // 64 = 8b * 8h
    int b = bid >> 3, h = bid & 7;
    int t = threadIdx.x, i = t >> 4, j = t & 15;
    float gsum = 0.f, qs = 0.f, ks = 0.f;
    for (int ch = 0; ch < 64; ch++) {
        const float* base = stats + ((size_t)(b*64 + ch)*8 + h)*288;
        gsum += base[i*16 + j];
        qs   += base[256 + i];
        ks   += base[272 + j];
    }
    float et  = expf(temp[h]);
    float sim = gsum * et / (fmaxf(sqrtf(qs), 1e-12f) * fmaxf(sqrtf(ks), 1e-12f));
    float m = sim;
    #pragma unroll
    for (int d = 1; d < 16; d <<= 1) m = fmaxf(m, __shfl_xor(m, d, 16));
    float e = expf(sim - m);
    float ssum = e;
    #pragma unroll
    for (int d = 1; d < 16; d <<= 1) ssum += __shfl_xor(ssum, d, 16);
    attn[((size_t)(b*8 + h)*16 + i)*16 + j] = e / ssum;
}

// ---------- kernel 4: w_eff[b][o][c] = sum_i w_out[o][h*16+i]*attn[b][h][i][j] ----------
__global__ __launch_bounds__(256) void k_weff(const float* __restrict__ attn,
    const float* __restrict__ wout, bf16_t* __restrict__ weff)
{
    __shared__ float at[2048];
    int bid = blockIdx.x;           // 256 = 8b * 32
    int b = bid >> 5, ob = (bid & 31)*32;
    int t = threadIdx.x;
    #pragma unroll
    for (int r = 0; r < 8; r++) at[t + 256*r] = attn[(size_t)b*2048 + t + 256*r];
    __syncthreads();
    int c = t & 127, h = c >> 4, j = c & 15, oo = (t >> 7)*16;
    #pragma unroll
    for (int m = 0; m < 16; m++) {
        int o = ob + oo + m;
        float acc = 0.f;
        #pragma unroll
        for (int i2 = 0; i2 < 16; i2++)
            acc += wout[(size_t)o*INNER + h*16 + i2] * at[(h*16 + i2)*16 + j];
        weff[((size_t)b*DIM + o)*INNER + c] = (bf16_t)acc;
    }
}

// ---------- kernel 5: output GEMM  per b: (4096x128)x(128x1024), fp32 out ----------
__global__ __launch_bounds__(256) void k_out_gemm(const bf16_t* __restrict__ qkv,
    const bf16_t* __restrict__ weff, float* __restrict__ out)
{
    __shared__ bf16_t Al[128*136];
    __shared__ bf16_t Bl[128*136];
    int bid = blockIdx.x;           // 2048 = 8b * 32mt * 8nt
    int b = bid >> 8, rem = bid & 255;
    int mt = rem >> 3, nt = rem & 7;
    int tok0 = mt*128, o0 = nt*128;
    int t = threadIdx.x;
    #pragma unroll
    for (int rd = 0; rd < 8; rd++) {
        int r  = (t >> 4) + 16*rd;
        int c8 = (t & 15) * 8;
        *reinterpret_cast<uint4*>(&Al[r*136 + c8]) =
            *reinterpret_cast<const uint4*>(
                qkv + ((size_t)b*NTOK + tok0 + r)*QKVC + 256 + c8);   // v cols
        *reinterpret_cast<uint4*>(&Bl[r*136 + c8]) =
            *reinterpret_cast<const uint4*>(
                weff + ((size_t)b*DIM + o0 + r)*INNER + c8);
    }
    __syncthreads();
    int w = t >> 6, lane = t & 63, lr = lane & 15, lg = lane >> 4;
    int wr = (w & 1)*64, wc = (w >> 1)*64;
    f32x4 acc[4][4] = {};
    #pragma unroll
    for (int kk = 0; kk < 4; kk++) {
        int kb = kk*32 + lg*8;
        bf16x8 af[4], bfr[4];
        #pragma unroll
        for (int mi = 0; mi < 4; mi++)
            af[mi] = *reinterpret_cast<const bf16x8*>(&Al[(wr + mi*16 + lr)*136 + kb]);
        #pragma unroll
        for (int ni = 0; ni < 4; ni++)
            bfr[ni] = *reinterpret_cast<const bf16x8*>(&Bl[(wc + ni*16 + lr)*136 + kb]);
        #pragma unroll
        for (int mi = 0; mi < 4; mi++)
            #pragma unroll
            for (int ni = 0; ni < 4; ni++)
                acc[mi][ni] = __builtin_amdgcn_mfma_f32_16x16x32_bf16(
                    af[mi], bfr[ni], acc[mi][ni], 0, 0, 0);
    }
    #pragma unroll
    for (int mi = 0; mi < 4; mi++)
        #pragma unroll
        for (int ni = 0; ni < 4; ni++) {
            int col_g = o0 + wc + ni*16 + lr;
            #pragma unroll
            for (int r = 0; r < 4; r++) {
                int row_g = tok0 + wr + mi*16 + lg*4 + r;
                out[((size_t)b*NTOK + row_g)*DIM + col_g] = acc[mi][ni][r];
            }
        }
}

extern "C" void kernel_launch(void* const* d_in, const int* in_sizes, int n_in,
                              void* d_out, int out_size, void* d_ws, size_t ws_size,
                              hipStream_t stream)
{
    const float* x    = (const float*)d_in[0];   // 8*4096*1024
    const float* nw   = (const float*)d_in[1];   // 1024
    const float* wq   = (const float*)d_in[2];   // 384*1024
    const float* temp = (const float*)d_in[3];   // 8
    const float* wout = (const float*)d_in[4];   // 1024*128
    float* out = (float*)d_out;

    char* ws = (char*)d_ws;
    bf16_t* wqb   = (bf16_t*)(ws + OFF_WQ);
    bf16_t* xb    = (bf16_t*)(ws + OFF_XB);
    bf16_t* qkv   = (bf16_t*)(ws + OFF_QKV);
    float*  stats = (float*)(ws + OFF_STATS);
    float*  attn  = (float*)(ws + OFF_ATTN);
    bf16_t* weff  = (bf16_t*)(ws + OFF_WEFF);

    k_prep     <<<8576, 256, 0, stream>>>(x, wq, nw, xb, wqb);
    k_qkv_gemm <<<768,  256, 0, stream>>>(xb, wqb, qkv);
    k_stats    <<<512,  256, 0, stream>>>(qkv, stats);
    k_attn     <<<64,   256, 0, stream>>>(stats, temp, attn);
    k_weff     <<<256,  256, 0, stream>>>(attn, wout, weff);
    k_out_gemm <<<2048, 256, 0, stream>>>(qkv, weff, out);
}

// Round 16
// 101.903 us; speedup vs baseline: 1.3108x; 1.3108x over previous
//
#include <hip/hip_runtime.h>
#include <hip/hip_bf16.h>
#include <stdint.h>

typedef __bf16 bf16_t;
typedef __bf16 bf16x8 __attribute__((ext_vector_type(8)));
typedef float  f32x4  __attribute__((ext_vector_type(4)));

#define DIM    1024
#define NTOK   4096
#define NB     8
#define ROWS   (NB*NTOK)   // 32768
#define QKVC   384
#define INNER  128

// global -> LDS direct copy, 16B per lane (dest = wave-uniform base + lane*16)
#define GLD16(g, l) __builtin_amdgcn_global_load_lds( \
    (const __attribute__((address_space(1))) void*)(g), \
    (__attribute__((address_space(3))) void*)(l), 16, 0, 0)

// workspace offsets (bytes)
#define OFF_WQ    131072u      // 384*1024 bf16   (768 KB)
#define OFF_QKV   1048576u     // 32768*384 bf16  (24 MB; only v cols written)
#define OFF_STATS 26214400u    // 256 chunks * 8 heads * 288 f32
#define OFF_ATTN  30932992u    // 8*8*16*16 f32
#define OFF_WEFF  30998528u    // 8*1024*128 bf16

// ---------- kernel 0: w_qkv * norm_weight -> bf16 ----------
__global__ __launch_bounds__(256) void k_wconv(const float* __restrict__ wq,
    const float* __restrict__ nw, bf16_t* __restrict__ wqb)
{
    int o = blockIdx.x;            // 384 rows
    int c = threadIdx.x * 4;
    float4 wv = *reinterpret_cast<const float4*>(wq + (size_t)o*DIM + c);
    float4 nv = *reinterpret_cast<const float4*>(nw + c);
    bf16_t* dst = wqb + (size_t)o*DIM + c;
    dst[0]=(bf16_t)(wv.x*nv.x); dst[1]=(bf16_t)(wv.y*nv.y);
    dst[2]=(bf16_t)(wv.z*nv.z); dst[3]=(bf16_t)(wv.w*nv.w);
}

// ---------- kernel 1: FUSED RMSNorm + QKV GEMM + Gram stats ----------
// Body = R8's measured-best structure (77.7 us). New: q,k cols (<256) go to
// an LDS tile reusing the dead Bl region (all Bl reads complete at the srow
// barrier); a per-wave (head=wave) Gram phase computes sim partials + qsq/ksq
// via 4x mfma_16x16x32 over the block's 128 tokens — k_stats kernel removed,
// 16MB qkv q,k writes + 16MB stats re-read eliminated.
__global__ __launch_bounds__(512, 2) void k_qkv_gemm(const float* __restrict__ x,
    const bf16_t* __restrict__ wqb, bf16_t* __restrict__ qkv,
    float* __restrict__ stats)
{
    __shared__ bf16_t Al[2][128*64];   // 2 x 16 KB
    __shared__ bf16_t Bl[2][384*64];   // 2 x 48 KB (reused as 128x256 qk tile)
    __shared__ float srow[128];
    int mt = blockIdx.x;               // 256 blocks; chunk = 128 tokens
    int row0 = mt*128;
    int t = threadIdx.x;
    int lane = t & 63, lr = lane & 15, lg = lane >> 4;
    int w = t >> 6, wm = w >> 2, wn = w & 3;   // 2M x 4N wave grid

    // ---- A staging (regs): thread t owns row rA, fp32 elems fo..fo+15 of 64
    int rA = t >> 2;                   // 0..127
    int fo = (t & 3) * 16;
    const float* xrow = x + (size_t)(row0 + rA)*DIM + fo;
    int ws0 = ((t & 3)*2)     ^ (rA & 7);
    int ws1 = ((t & 3)*2 + 1) ^ (rA & 7);

    // ---- B staging (global_load_lds)
    int srB = t >> 3;                  // 0..63
    int sk8 = ((t & 7) ^ (srB & 7)) * 8;
    const bf16_t* bbase = wqb + (size_t)srB*DIM + sk8;
    int ldsoff = (t & ~63) * 8;        // wave-uniform dest base (elems)

    int rsw = lr & 7;                  // read-side slot XOR

    float4 u0, u1, u2, u3;             // 16 fp32 staging regs

#define LOADA(kt) do {                                                   \
        const float4* _xs = reinterpret_cast<const float4*>(xrow + (kt)*64); \
        u0 = _xs[0]; u1 = _xs[1]; u2 = _xs[2]; u3 = _xs[3];              \
    } while (0)

#define STAGEB(buf, kt) do {                                             \
        int _ko = (kt)*64;                                               \
        _Pragma("unroll")                                                \
        for (int _c = 0; _c < 6; _c++)                                   \
            GLD16(bbase + _ko + (size_t)(64*_c)*DIM,                     \
                  &Bl[buf][ldsoff + _c*4096]);                           \
    } while (0)

#define WRITEA(buf) do {                                                 \
        ssq += u0.x*u0.x + u0.y*u0.y + u0.z*u0.z + u0.w*u0.w             \
             + u1.x*u1.x + u1.y*u1.y + u1.z*u1.z + u1.w*u1.w             \
             + u2.x*u2.x + u2.y*u2.y + u2.z*u2.z + u2.w*u2.w             \
             + u3.x*u3.x + u3.y*u3.y + u3.z*u3.z + u3.w*u3.w;            \
        bf16x8 v0, v1;                                                   \
        v0[0]=(bf16_t)u0.x; v0[1]=(bf16_t)u0.y; v0[2]=(bf16_t)u0.z;      \
        v0[3]=(bf16_t)u0.w; v0[4]=(bf16_t)u1.x; v0[5]=(bf16_t)u1.y;      \
        v0[6]=(bf16_t)u1.z; v0[7]=(bf16_t)u1.w;                          \
        v1[0]=(bf16_t)u2.x; v1[1]=(bf16_t)u2.y; v1[2]=(bf16_t)u2.z;      \
        v1[3]=(bf16_t)u2.w; v1[4]=(bf16_t)u3.x; v1[5]=(bf16_t)u3.y;      \
        v1[6]=(bf16_t)u3.z; v1[7]=(bf16_t)u3.w;                          \
        *reinterpret_cast<bf16x8*>(&Al[buf][rA*64 + ws0*8]) = v0;        \
        *reinterpret_cast<bf16x8*>(&Al[buf][rA*64 + ws1*8]) = v1;        \
    } while (0)

    float ssq = 0.f;
    f32x4 acc[4][6] = {};

    // prologue: tile 0
    LOADA(0);
    STAGEB(0, 0);
    WRITEA(0);
    __syncthreads();

    for (int kt = 0; kt < 16; kt++) {
        int cur = kt & 1;
        if (kt < 15) {
            LOADA(kt + 1);
            STAGEB(cur ^ 1, kt + 1);
        }
        #pragma unroll
        for (int kk = 0; kk < 2; kk++) {
            int kb = ((kk*4 + lg) ^ rsw) * 8;
            bf16x8 af[4], bfr[6];
            #pragma unroll
            for (int mi = 0; mi < 4; mi++)
                af[mi] = *reinterpret_cast<const bf16x8*>(
                    &Al[cur][(wm*64 + mi*16 + lr)*64 + kb]);
            #pragma unroll
            for (int ni = 0; ni < 6; ni++)
                bfr[ni] = *reinterpret_cast<const bf16x8*>(
                    &Bl[cur][(wn*96 + ni*16 + lr)*64 + kb]);
            #pragma unroll
            for (int mi = 0; mi < 4; mi++)
                #pragma unroll
                for (int ni = 0; ni < 6; ni++)
                    acc[mi][ni] = __builtin_amdgcn_mfma_f32_16x16x32_bf16(
                        af[mi], bfr[ni], acc[mi][ni], 0, 0, 0);
        }
        if (kt < 15) WRITEA(cur ^ 1);
        __syncthreads();
    }
#undef LOADA
#undef STAGEB
#undef WRITEA

    // per-row sumsq: 4 consecutive threads share row rA
    ssq += __shfl_xor(ssq, 1, 64);
    ssq += __shfl_xor(ssq, 2, 64);
    if ((t & 3) == 0) srow[rA] = rsqrtf(ssq*(1.0f/DIM) + 1e-6f);
    __syncthreads();                    // also: all Bl reads done -> reusable

    // epilogue: v cols (>=256) -> global; q,k cols (<256) -> LDS qk tile
    bf16_t* qk = &Bl[0][0];             // 128 x 256 row-major (64 KB of 96)
    #pragma unroll
    for (int mi = 0; mi < 4; mi++)
        #pragma unroll
        for (int ni = 0; ni < 6; ni++) {
            int col_g = wn*96 + ni*16 + lr;
            #pragma unroll
            for (int rr = 0; rr < 4; rr++) {
                int rloc = wm*64 + mi*16 + lg*4 + rr;
                bf16_t val = (bf16_t)(acc[mi][ni][rr] * srow[rloc]);
                if (wn*96 + ni*16 >= 256)       // (wn,ni)-uniform branch
                    qkv[(size_t)(row0 + rloc)*QKVC + col_g] = val;
                else
                    qk[rloc*256 + col_g] = val;
            }
        }
    __syncthreads();

    // Gram phase: wave w = head h; gram[i][j] = sum_t q[t][h16+i]*k[t][h16+j]
    {
        int h = w;
        f32x4 g = {};
        #pragma unroll
        for (int ks = 0; ks < 4; ks++) {
            bf16x8 afr, bfr2;
            #pragma unroll
            for (int e = 0; e < 8; e++) {
                int tt = ks*32 + lg*8 + e;
                afr[e]  = qk[tt*256 + h*16 + lr];
                bfr2[e] = qk[tt*256 + 128 + h*16 + lr];
            }
            g = __builtin_amdgcn_mfma_f32_16x16x32_bf16(afr, bfr2, g, 0, 0, 0);
        }
        float* base = stats + ((size_t)mt*8 + h)*288;
        #pragma unroll
        for (int reg = 0; reg < 4; reg++)
            base[(lg*4 + reg)*16 + lr] = g[reg];   // row=lg*4+reg, col=lr
        float qs = 0.f, ks2 = 0.f;
        #pragma unroll
        for (int e = 0; e < 32; e++) {
            int tt = lg*32 + e;
            float qv = (float)qk[tt*256 + h*16 + lr];
            float kv = (float)qk[tt*256 + 128 + h*16 + lr];
            qs += qv*qv; ks2 += kv*kv;
        }
        qs  += __shfl_xor(qs, 16, 64);  qs  += __shfl_xor(qs, 32, 64);
        ks2 += __shfl_xor(ks2, 16, 64); ks2 += __shfl_xor(ks2, 32, 64);
        if (lane < 16) { base[256 + lr] = qs; base[272 + lr] = ks2; }
    }
}

// ---------- kernel 2: reduce partials, l2-normalize, temperature, softmax ----------
__global__ __launch_bounds__(256) void k_attn(const float* __restrict__ stats,
    const float* __restrict__ temp, float* __restrict__ attn)
{
    int bid = blockIdx.x;           // 64 = 8b * 8h
    int b = bid >> 3, h = bid & 7;
    int t = threadIdx.x, i = t >> 4, j = t & 15;
    float gsum = 0.f, qs = 0.f, ks = 0.f;
    for (int ch = 0; ch < 32; ch++) {        // 32 chunks of 128 tokens
        const float* base = stats + ((size_t)(b*32 + ch)*8 + h)*288;
        gsum += base[i*16 + j];
        qs   += base[256 + i];
        ks   += base[272 + j];
    }
    float et  = expf(temp[h]);
    float sim = gsum * et / (fmaxf(sqrtf(qs), 1e-12f) * fmaxf(sqrtf(ks), 1e-12f));
    float m = sim;
    #pragma unroll
    for (int d = 1; d < 16; d <<= 1) m = fmaxf(m, __shfl_xor(m, d, 16));
    float e = expf(sim - m);
    float ssum = e;
    #pragma unroll
    for (int d = 1; d < 16; d <<= 1) ssum += __shfl_xor(ssum, d, 16);
    attn[((size_t)(b*8 + h)*16 + i)*16 + j] = e / ssum;
}

// ---------- kernel 3: w_eff[b][o][c] = sum_i w_out[o][h*16+i]*attn[b][h][i][j] ----------
__global__ __launch_bounds__(256) void k_weff(const float* __restrict__ attn,
    const float* __restrict__ wout, bf16_t* __restrict__ weff)
{
    __shared__ float at[2048];
    int bid = blockIdx.x;           // 256 = 8b * 32
    int b = bid >> 5, ob = (bid & 31)*32;
    int t = threadIdx.x;
    #pragma unroll
    for (int r = 0; r < 8; r++) at[t + 256*r] = attn[(size_t)b*2048 + t + 256*r];
    __syncthreads();
    int c = t & 127, h = c >> 4, j = c & 15, oo = (t >> 7)*16;
    #pragma unroll
    for (int m = 0; m < 16; m++) {
        int o = ob + oo + m;
        float acc = 0.f;
        #pragma unroll
        for (int i2 = 0; i2 < 16; i2++)
            acc += wout[(size_t)o*INNER + h*16 + i2] * at[(h*16 + i2)*16 + j];
        weff[((size_t)b*DIM + o)*INNER + c] = (bf16_t)acc;
    }
}

// ---------- kernel 4: output GEMM  per b: (4096x128)x(128x1024), fp32 out ----------
__global__ __launch_bounds__(256) void k_out_gemm(const bf16_t* __restrict__ qkv,
    const bf16_t* __restrict__ weff, float* __restrict__ out)
{
    __shared__ bf16_t Al[128*136];
    __shared__ bf16_t Bl[128*136];
    int bid = blockIdx.x;           // 2048 = 8b * 32mt * 8nt
    int b = bid >> 8, rem = bid & 255;
    int mt = rem >> 3, nt = rem & 7;
    int tok0 = mt*128, o0 = nt*128;
    int t = threadIdx.x;
    #pragma unroll
    for (int rd = 0; rd < 8; rd++) {
        int r  = (t >> 4) + 16*rd;
        int c8 = (t & 15) * 8;
        *reinterpret_cast<uint4*>(&Al[r*136 + c8]) =
            *reinterpret_cast<const uint4*>(
                qkv + ((size_t)b*NTOK + tok0 + r)*QKVC + 256 + c8);   // v cols
        *reinterpret_cast<uint4*>(&Bl[r*136 + c8]) =
            *reinterpret_cast<const uint4*>(
                weff + ((size_t)b*DIM + o0 + r)*INNER + c8);
    }
    __syncthreads();
    int w = t >> 6, lane = t & 63, lr = lane & 15, lg = lane >> 4;
    int wr = (w & 1)*64, wc = (w >> 1)*64;
    f32x4 acc[4][4] = {};
    #pragma unroll
    for (int kk = 0; kk < 4; kk++) {
        int kb = kk*32 + lg*8;
        bf16x8 af[4], bfr[4];
        #pragma unroll
        for (int mi = 0; mi < 4; mi++)
            af[mi] = *reinterpret_cast<const bf16x8*>(&Al[(wr + mi*16 + lr)*136 + kb]);
        #pragma unroll
        for (int ni = 0; ni < 4; ni++)
            bfr[ni] = *reinterpret_cast<const bf16x8*>(&Bl[(wc + ni*16 + lr)*136 + kb]);
        #pragma unroll
        for (int mi = 0; mi < 4; mi++)
            #pragma unroll
            for (int ni = 0; ni < 4; ni++)
                acc[mi][ni] = __builtin_amdgcn_mfma_f32_16x16x32_bf16(
                    af[mi], bfr[ni], acc[mi][ni], 0, 0, 0);
    }
    #pragma unroll
    for (int mi = 0; mi < 4; mi++)
        #pragma unroll
        for (int ni = 0; ni < 4; ni++) {
            int col_g = o0 + wc + ni*16 + lr;
            #pragma unroll
            for (int r = 0; r < 4; r++) {
                int row_g = tok0 + wr + mi*16 + lg*4 + r;
                out[((size_t)b*NTOK + row_g)*DIM + col_g] = acc[mi][ni][r];
            }
        }
}

extern "C" void kernel_launch(void* const* d_in, const int* in_sizes, int n_in,
                              void* d_out, int out_size, void* d_ws, size_t ws_size,
                              hipStream_t stream)
{
    const float* x    = (const float*)d_in[0];   // 8*4096*1024
    const float* nw   = (const float*)d_in[1];   // 1024
    const float* wq   = (const float*)d_in[2];   // 384*1024
    const float* temp = (const float*)d_in[3];   // 8
    const float* wout = (const float*)d_in[4];   // 1024*128
    float* out = (float*)d_out;

    char* ws = (char*)d_ws;
    bf16_t* wqb   = (bf16_t*)(ws + OFF_WQ);
    bf16_t* qkv   = (bf16_t*)(ws + OFF_QKV);
    float*  stats = (float*)(ws + OFF_STATS);
    float*  attn  = (float*)(ws + OFF_ATTN);
    bf16_t* weff  = (bf16_t*)(ws + OFF_WEFF);

    k_wconv    <<<384,  256, 0, stream>>>(wq, nw, wqb);
    k_qkv_gemm <<<256,  512, 0, stream>>>(x, wqb, qkv, stats);
    k_attn     <<<64,   256, 0, stream>>>(stats, temp, attn);
    k_weff     <<<256,  256, 0, stream>>>(attn, wout, weff);
    k_out_gemm <<<2048, 256, 0, stream>>>(qkv, weff, out);
}